// Round 1
// baseline (10309.566 us; speedup 1.0000x reference)
//
#include <hip/hip_runtime.h>
#include <hip/hip_cooperative_groups.h>
#include <float.h>
#include <math.h>

namespace cg = cooperative_groups;

#define H      1024     // LATENT
#define V      32000    // VOCAB
#define NCOND  64
#define NLIN   1024
#define ZCN    1088     // LIN + COND
#define NSTEP  128
#define NBLK   256
#define NTHR   1024
#define WPB    16       // waves per block
#define GWAVES (NBLK * WPB)   // 4096 waves total

__device__ __forceinline__ float waveReduceSum(float v) {
#pragma unroll
    for (int off = 32; off > 0; off >>= 1)
        v += __shfl_down(v, off, 64);
    return v;
}

extern "C" __global__ void __launch_bounds__(NTHR)
decoder_kernel(const float* __restrict__ z, const float* __restrict__ cnd,
               const float* __restrict__ l1W, const float* __restrict__ l1b,
               const float* __restrict__ emb, const float* __restrict__ Wih,
               const float* __restrict__ Whh, const float* __restrict__ bih,
               const float* __restrict__ bhh, const float* __restrict__ fcW,
               const float* __restrict__ fcb, float* __restrict__ out,
               float* __restrict__ ws)
{
    cg::grid_group grid = cg::this_grid();

    __shared__ __align__(16) float s_x[H];
    __shared__ __align__(16) float s_h[H];
    __shared__ __align__(16) float s_c[H];
    __shared__ __align__(16) float s_zc[ZCN];
    __shared__ float s_wval[WPB];
    __shared__ int   s_widx[WPB];
    __shared__ int   s_tok;

    const int tid  = threadIdx.x;
    const int lane = tid & 63;
    const int wv   = tid >> 6;
    const int gw   = blockIdx.x * WPB + wv;   // global wave id, [0, 4096)

    float* ws_gates = ws;                     // 4096 floats
    float* ws_h0    = ws + 4096;              // 1024 floats
    float* ws_bval  = ws + 5120;              // 256 floats
    int*   ws_bidx  = (int*)(ws + 5120 + NBLK); // 256 ints

    // ---------- prologue: h0 = l1_W @ [z;c] + l1_b ----------
    if (tid < NLIN)  s_zc[tid] = z[tid];
    if (tid < NCOND) s_zc[NLIN + tid] = cnd[tid];
    __syncthreads();

    if (gw < H) {
        const float* wr = l1W + (size_t)gw * ZCN;
        float acc = 0.f;
        for (int k = lane; k < ZCN; k += 64) acc += wr[k] * s_zc[k];
        acc = waveReduceSum(acc);
        if (lane == 0) ws_h0[gw] = acc + l1b[gw];
    }
    grid.sync();

    // init block-local state: h = h0, c = 0, x = relu(emb[SOS=0])
    for (int j = tid; j < H; j += NTHR) {
        s_h[j] = ws_h0[j];
        s_c[j] = 0.f;
        float e = emb[j];
        s_x[j] = e > 0.f ? e : 0.f;
    }
    __syncthreads();

    for (int step = 0; step < NSTEP; ++step) {
        // ---------- Stage A: gates[gw] = Wih[gw]@x + Whh[gw]@h + biases ----------
        {
            const float4* wi = (const float4*)(Wih + (size_t)gw * H);
            const float4* wh = (const float4*)(Whh + (size_t)gw * H);
            const float4* xv = (const float4*)s_x;
            const float4* hv = (const float4*)s_h;
            float acc = 0.f;
#pragma unroll
            for (int k = 0; k < 4; ++k) {
                int idx = k * 64 + lane;
                float4 a = wi[idx], b = xv[idx];
                acc += a.x*b.x + a.y*b.y + a.z*b.z + a.w*b.w;
                float4 a2 = wh[idx], b2 = hv[idx];
                acc += a2.x*b2.x + a2.y*b2.y + a2.z*b2.z + a2.w*b2.w;
            }
            acc = waveReduceSum(acc);
            if (lane == 0) ws_gates[gw] = acc + bih[gw] + bhh[gw];
        }
        grid.sync();

        // ---------- state update (each block redundantly, into its LDS) ----------
        {
            int j = tid;   // NTHR == H
            float gi = ws_gates[j];
            float gf = ws_gates[H + j];
            float gg = ws_gates[2 * H + j];
            float go = ws_gates[3 * H + j];
            float i_ = 1.f / (1.f + expf(-gi));
            float f_ = 1.f / (1.f + expf(-gf));
            float g_ = tanhf(gg);
            float o_ = 1.f / (1.f + expf(-go));
            float cn = f_ * s_c[j] + i_ * g_;
            s_c[j] = cn;
            s_h[j] = o_ * tanhf(cn);
        }
        __syncthreads();

        // ---------- Stage B: logits + argmax partials ----------
        {
            const float4* hv = (const float4*)s_h;
            float best = -FLT_MAX; int bidx = V;
            for (int r = gw; r < V; r += GWAVES) {
                const float4* wr = (const float4*)(fcW + (size_t)r * H);
                float acc = 0.f;
#pragma unroll
                for (int k = 0; k < 4; ++k) {
                    int idx = k * 64 + lane;
                    float4 a = wr[idx], b = hv[idx];
                    acc += a.x*b.x + a.y*b.y + a.z*b.z + a.w*b.w;
                }
                acc = waveReduceSum(acc);
                if (lane == 0) {
                    float lg = acc + fcb[r];
                    out[(size_t)step * V + r] = lg;
                    if (lg > best) { best = lg; bidx = r; }  // r increasing -> first-index ties
                }
            }
            if (lane == 0) { s_wval[wv] = best; s_widx[wv] = bidx; }
        }
        __syncthreads();
        if (tid == 0) {
            float bv = -FLT_MAX; int bi = V;
            for (int w = 0; w < WPB; ++w) {
                float v = s_wval[w]; int id = s_widx[w];
                if (v > bv || (v == bv && id < bi)) { bv = v; bi = id; }
            }
            ws_bval[blockIdx.x] = bv;
            ws_bidx[blockIdx.x] = bi;
        }
        grid.sync();

        // ---------- token select + next x (each block redundantly) ----------
        if (wv == 0) {
            float bv = -FLT_MAX; int bi = V;
            for (int k = lane; k < NBLK; k += 64) {
                float v = ws_bval[k]; int id = ws_bidx[k];
                if (v > bv || (v == bv && id < bi)) { bv = v; bi = id; }
            }
#pragma unroll
            for (int off = 32; off > 0; off >>= 1) {
                float ov = __shfl_down(bv, off, 64);
                int   oi = __shfl_down(bi, off, 64);
                if (ov > bv || (ov == bv && oi < bi)) { bv = ov; bi = oi; }
            }
            if (lane == 0) s_tok = bi;
        }
        __syncthreads();
        {
            int tok = s_tok;
            const float* er = emb + (size_t)tok * H;
            for (int j = tid; j < H; j += NTHR) {
                float e = er[j];
                s_x[j] = e > 0.f ? e : 0.f;
            }
        }
        __syncthreads();
    }
}

extern "C" void kernel_launch(void* const* d_in, const int* in_sizes, int n_in,
                              void* d_out, int out_size, void* d_ws, size_t ws_size,
                              hipStream_t stream) {
    const float* z   = (const float*)d_in[0];
    const float* c   = (const float*)d_in[1];
    const float* l1W = (const float*)d_in[2];
    const float* l1b = (const float*)d_in[3];
    const float* emb = (const float*)d_in[4];
    const float* Wih = (const float*)d_in[5];
    const float* Whh = (const float*)d_in[6];
    const float* bih = (const float*)d_in[7];
    const float* bhh = (const float*)d_in[8];
    const float* fcW = (const float*)d_in[9];
    const float* fcb = (const float*)d_in[10];
    float* out = (float*)d_out;
    float* ws  = (float*)d_ws;

    void* args[] = { &z, &c, &l1W, &l1b, &emb, &Wih, &Whh, &bih, &bhh,
                     &fcW, &fcb, &out, &ws };
    hipLaunchCooperativeKernel((void*)decoder_kernel, dim3(NBLK), dim3(NTHR),
                               args, 0, stream);
}